// Round 1
// baseline (490.372 us; speedup 1.0000x reference)
//
#include <hip/hip_runtime.h>
#include <hip/hip_bf16.h>

// GraphAttentionEncoder: 2x GATConv (shared edges) + gated mix + residual + LN
// N=50000 nodes, DIM=128, H=4 heads, C=32, E=800000 edges (+N self loops)
//
// Pipeline (all in one launch, CSR rebuilt every call since ws is re-poisoned):
//  k_xprep : x -> bf16 copy, deg[i]=1 (self loop)
//  k_wprep : [W1|W2] -> Wb[col][k] bf16 (B^T layout for MFMA)
//  k_count : deg[dst]++ over edges
//  k_scan  : single-block exclusive scan -> offsets, cursor
//  k_fill  : counting-sort edges by dst -> sorted src list
//  k_gemm  : h = x @ [W1|W2] via mfma_f32_16x16x32_bf16 (m97 B^T pattern), bf16 out
//  k_logits: per-node per-head att dots (e_src, e_dst) for both layers
//  k_agg   : one wave per node: online-softmax aggregation over CSR edges for
//            both layers -> bias -> gate softmax -> residual -> LayerNorm -> out

typedef unsigned short u16;
typedef __bf16 bf16x8 __attribute__((ext_vector_type(8)));
typedef float f32x4 __attribute__((ext_vector_type(4)));

#define LRELU_SLOPE 0.2f
#define LN_EPS 1e-5f

__device__ __forceinline__ float bf2f(u16 u) {
    union { unsigned int i; float f; } v; v.i = ((unsigned int)u) << 16; return v.f;
}
__device__ __forceinline__ u16 f2bf(float f) {
    union { float f; unsigned int i; } v; v.f = f;
    unsigned int lsb = (v.i >> 16) & 1u;
    v.i += 0x7FFFu + lsb;                 // round-to-nearest-even
    return (u16)(v.i >> 16);
}

__global__ void k_xprep(const float* __restrict__ x, u16* __restrict__ xb,
                        int* __restrict__ deg, int n128, int n) {
    int i = blockIdx.x * blockDim.x + threadIdx.x;
    if (i < n128) xb[i] = f2bf(x[i]);
    if (i < n) deg[i] = 1;                // self loop
}

// Wb[col][k] = W[k][col]  (col in [0,256): 0-127 -> W1, 128-255 -> W2)
__global__ void k_wprep(const float* __restrict__ W1, const float* __restrict__ W2,
                        u16* __restrict__ wb) {
    int i = blockIdx.x * blockDim.x + threadIdx.x;   // 32768
    int col = i >> 7, k = i & 127;
    float v = (col < 128) ? W1[k * 128 + col] : W2[k * 128 + (col - 128)];
    wb[i] = f2bf(v);
}

__global__ void k_count(const int* __restrict__ ei, int* __restrict__ deg, int E) {
    int i = blockIdx.x * blockDim.x + threadIdx.x;
    if (i < E) atomicAdd(&deg[ei[E + i]], 1);
}

#define SCAN_T 1024
__global__ void k_scan(const int* __restrict__ deg, int* __restrict__ offs,
                       int* __restrict__ cursor, int n) {
    __shared__ int sums[SCAN_T];
    int t = threadIdx.x;
    int per = (n + SCAN_T - 1) / SCAN_T;
    int base = t * per;
    int s = 0;
    for (int i = 0; i < per; i++) { int idx = base + i; if (idx < n) s += deg[idx]; }
    sums[t] = s;
    __syncthreads();
    for (int off = 1; off < SCAN_T; off <<= 1) {
        int v = (t >= off) ? sums[t - off] : 0;
        __syncthreads();
        sums[t] += v;
        __syncthreads();
    }
    int incl = sums[t];
    int run = incl - s;                    // exclusive prefix at base
    for (int i = 0; i < per; i++) {
        int idx = base + i;
        if (idx < n) { offs[idx] = run; cursor[idx] = run; run += deg[idx]; }
    }
    if (t == SCAN_T - 1) offs[n] = incl;
}

__global__ void k_fill(const int* __restrict__ ei, int* __restrict__ cursor,
                       int* __restrict__ ssrc, int E, int n) {
    int i = blockIdx.x * blockDim.x + threadIdx.x;
    if (i >= E + n) return;
    int s, d;
    if (i < E) { s = ei[i]; d = ei[E + i]; } else { s = i - E; d = s; }
    int pos = atomicAdd(&cursor[d], 1);
    ssrc[pos] = s;
}

// MFMA GEMM: A = xb (M=n x K=128), B^T = wb (256 x 128). Block: 64 rows, 4 waves.
// Wave w handles rows [brow+16w, brow+16w+16), all 16 n-tiles, K=128 in 4 steps.
#define RS 152   // LDS row stride in bf16 elems (304 B) -> 2-way bank alias only
__global__ __launch_bounds__(256) void k_gemm(const u16* __restrict__ xb,
                                              const u16* __restrict__ wb,
                                              u16* __restrict__ h1b,
                                              u16* __restrict__ h2b, int n) {
    __shared__ u16 lA[64 * RS];
    __shared__ u16 lB[128 * RS];
    int tid = threadIdx.x;
    int brow = blockIdx.x * 64;

    // stage A: 64 rows x 128 bf16 = 1024 16B-chunks
    for (int c = tid; c < 1024; c += 256) {
        int r = c >> 4, o = c & 15;
        int gr = brow + r; if (gr >= n) gr = n - 1;
        *(int4*)(&lA[r * RS + o * 8]) = *(const int4*)(&xb[gr * 128 + o * 8]);
    }

    int wave = tid >> 6, lane = tid & 63;
    int quad = lane >> 4, r16 = lane & 15;

    f32x4 acc[16];
#pragma unroll
    for (int t = 0; t < 16; t++) acc[t] = (f32x4){0.f, 0.f, 0.f, 0.f};
    bf16x8 a[4];

    for (int half = 0; half < 2; half++) {
        // stage B half: 128 rows x 128 bf16 = 2048 chunks
        for (int c = tid; c < 2048; c += 256) {
            int r = c >> 4, o = c & 15;
            *(int4*)(&lB[r * RS + o * 8]) = *(const int4*)(&wb[(half * 128 + r) * 128 + o * 8]);
        }
        __syncthreads();
        if (half == 0) {
            const u16* ab = &lA[(wave * 16 + r16) * RS + quad * 8];
#pragma unroll
            for (int ks = 0; ks < 4; ks++) a[ks] = *(const bf16x8*)(ab + ks * 32);
        }
#pragma unroll
        for (int t = 0; t < 8; t++) {
            const u16* bb = &lB[(t * 16 + r16) * RS + quad * 8];
#pragma unroll
            for (int ks = 0; ks < 4; ks++) {
                bf16x8 b = *(const bf16x8*)(bb + ks * 32);
                acc[half * 8 + t] =
                    __builtin_amdgcn_mfma_f32_16x16x32_bf16(a[ks], b, acc[half * 8 + t], 0, 0, 0);
            }
        }
        __syncthreads();
    }

    // epilogue: C/D layout col=lane&15, row=quad*4+reg
    int row0 = brow + wave * 16 + quad * 4;
#pragma unroll
    for (int t = 0; t < 16; t++) {
        int col = t * 16 + r16;
#pragma unroll
        for (int g = 0; g < 4; g++) {
            int gr = row0 + g;
            if (gr < n) {
                u16 v = f2bf(acc[t][g]);
                if (col < 128) h1b[gr * 128 + col] = v;
                else           h2b[gr * 128 + col - 128] = v;
            }
        }
    }
}

__global__ void k_logits(const u16* __restrict__ h1b, const u16* __restrict__ h2b,
                         const float* __restrict__ as1, const float* __restrict__ ad1,
                         const float* __restrict__ as2, const float* __restrict__ ad2,
                         float* __restrict__ es1, float* __restrict__ ed1,
                         float* __restrict__ es2, float* __restrict__ ed2, int n) {
    int i = blockIdx.x * blockDim.x + threadIdx.x;
    if (i >= n * 8) return;
    int node = i >> 3, layer = (i >> 2) & 1, head = i & 3;
    const u16* hp = (layer ? h2b : h1b) + node * 128 + head * 32;
    const float* asp = (layer ? as2 : as1) + head * 32;
    const float* adp = (layer ? ad2 : ad1) + head * 32;
    float es = 0.f, ed = 0.f;
#pragma unroll
    for (int c = 0; c < 32; c++) {
        float v = bf2f(hp[c]);
        es += v * asp[c];
        ed += v * adp[c];
    }
    if (layer) { es2[node * 4 + head] = es; ed2[node * 4 + head] = ed; }
    else       { es1[node * 4 + head] = es; ed1[node * 4 + head] = ed; }
}

__device__ __forceinline__ float wred(float v) {
#pragma unroll
    for (int off = 32; off; off >>= 1) v += __shfl_xor(v, off, 64);
    return v;
}

__device__ __forceinline__ void online_upd(float& m, float& l, float& a,
                                           float e, float v) {
    float mn = fmaxf(m, e);
    float sc = __expf(m - mn);
    float p  = __expf(e - mn);
    l = l * sc + p;
    a = a * sc + p * v;
    m = mn;
}

// one wave per node
__global__ __launch_bounds__(256) void k_agg(
    const int* __restrict__ offs, const int* __restrict__ ssrc,
    const u16* __restrict__ h1b, const u16* __restrict__ h2b,
    const float* __restrict__ es1, const float* __restrict__ ed1,
    const float* __restrict__ es2, const float* __restrict__ ed2,
    const float* __restrict__ b1, const float* __restrict__ b2,
    const float* __restrict__ gW, const float* __restrict__ gb,
    const float* __restrict__ x, const float* __restrict__ gamma,
    const float* __restrict__ beta, float* __restrict__ out, int n) {
    int wave = threadIdx.x >> 6, lane = threadIdx.x & 63;
    int node = blockIdx.x * 4 + wave;
    if (node >= n) return;

    int ha = lane >> 5;       // head for col = lane
    int hb = 2 + ha;          // head for col = 64+lane
    float ed1a = ed1[node * 4 + ha], ed1b = ed1[node * 4 + hb];
    float ed2a = ed2[node * 4 + ha], ed2b = ed2[node * 4 + hb];

    float m1a = -1e30f, m1b = -1e30f, m2a = -1e30f, m2b = -1e30f;
    float l1a = 0.f, l1b = 0.f, l2a = 0.f, l2b = 0.f;
    float a1a = 0.f, a1b = 0.f, a2a = 0.f, a2b = 0.f;

    int beg = offs[node], end = offs[node + 1];
    for (int k = beg; k < end; k++) {
        int j = ssrc[k];
        float e1a = es1[j * 4 + ha] + ed1a;
        float e1b = es1[j * 4 + hb] + ed1b;
        float e2a = es2[j * 4 + ha] + ed2a;
        float e2b = es2[j * 4 + hb] + ed2b;
        e1a = (e1a > 0.f) ? e1a : LRELU_SLOPE * e1a;
        e1b = (e1b > 0.f) ? e1b : LRELU_SLOPE * e1b;
        e2a = (e2a > 0.f) ? e2a : LRELU_SLOPE * e2a;
        e2b = (e2b > 0.f) ? e2b : LRELU_SLOPE * e2b;
        float v1a = bf2f(h1b[j * 128 + lane]);
        float v1b = bf2f(h1b[j * 128 + 64 + lane]);
        float v2a = bf2f(h2b[j * 128 + lane]);
        float v2b = bf2f(h2b[j * 128 + 64 + lane]);
        online_upd(m1a, l1a, a1a, e1a, v1a);
        online_upd(m1b, l1b, a1b, e1b, v1b);
        online_upd(m2a, l2a, a2a, e2a, v2a);
        online_upd(m2b, l2b, a2b, e2b, v2b);
    }

    float o1a = a1a / l1a + b1[lane];
    float o1b = a1b / l1b + b1[64 + lane];
    float o2a = a2a / l2a + b2[lane];
    float o2b = a2b / l2b + b2[64 + lane];

    // gate logits: concat(out1,out2) @ gate_W(256x2) + gate_b
    float p0 = o1a * gW[2 * lane] + o1b * gW[2 * (64 + lane)] +
               o2a * gW[2 * (128 + lane)] + o2b * gW[2 * (192 + lane)];
    float p1 = o1a * gW[2 * lane + 1] + o1b * gW[2 * (64 + lane) + 1] +
               o2a * gW[2 * (128 + lane) + 1] + o2b * gW[2 * (192 + lane) + 1];
    p0 = wred(p0) + gb[0];
    p1 = wred(p1) + gb[1];
    float mg = fmaxf(p0, p1);
    float eg0 = __expf(p0 - mg), eg1 = __expf(p1 - mg);
    float g0 = eg0 / (eg0 + eg1), g1 = 1.f - g0;

    float ya = x[node * 128 + lane] + g0 * o1a + g1 * o2a;
    float yb = x[node * 128 + 64 + lane] + g0 * o1b + g1 * o2b;

    float s  = wred(ya + yb);
    float ss = wred(ya * ya + yb * yb);
    float mean = s * (1.f / 128.f);
    float var  = ss * (1.f / 128.f) - mean * mean;
    float rstd = rsqrtf(var + LN_EPS);
    out[node * 128 + lane]      = (ya - mean) * rstd * gamma[lane] + beta[lane];
    out[node * 128 + 64 + lane] = (yb - mean) * rstd * gamma[64 + lane] + beta[64 + lane];
}

extern "C" void kernel_launch(void* const* d_in, const int* in_sizes, int n_in,
                              void* d_out, int out_size, void* d_ws, size_t ws_size,
                              hipStream_t stream) {
    const float* x   = (const float*)d_in[0];
    const int*   ei  = (const int*)d_in[1];
    const float* W1  = (const float*)d_in[2];
    const float* b1  = (const float*)d_in[3];
    const float* as1 = (const float*)d_in[4];
    const float* ad1 = (const float*)d_in[5];
    const float* W2  = (const float*)d_in[6];
    const float* b2  = (const float*)d_in[7];
    const float* as2 = (const float*)d_in[8];
    const float* ad2 = (const float*)d_in[9];
    const float* gW  = (const float*)d_in[10];
    const float* gb  = (const float*)d_in[11];
    const float* gamma = (const float*)d_in[12];
    const float* beta  = (const float*)d_in[13];
    float* out = (float*)d_out;

    int n = in_sizes[0] / 128;
    int E = in_sizes[1] / 2;
    int n128 = n * 128;

    char* p = (char*)d_ws;
    auto take = [&](size_t bytes) {
        char* q = p;
        p += (bytes + 255) & ~(size_t)255;
        return (void*)q;
    };
    u16* xb   = (u16*)take((size_t)n128 * 2);
    u16* wb   = (u16*)take((size_t)256 * 128 * 2);
    u16* h1b  = (u16*)take((size_t)n128 * 2);
    u16* h2b  = (u16*)take((size_t)n128 * 2);
    float* es1 = (float*)take((size_t)n * 4 * 4);
    float* ed1 = (float*)take((size_t)n * 4 * 4);
    float* es2 = (float*)take((size_t)n * 4 * 4);
    float* ed2 = (float*)take((size_t)n * 4 * 4);
    int* deg    = (int*)take((size_t)n * 4);
    int* offs   = (int*)take((size_t)(n + 1) * 4);
    int* cursor = (int*)take((size_t)n * 4);
    int* ssrc   = (int*)take((size_t)(E + n) * 4);

    k_xprep<<<(n128 + 255) / 256, 256, 0, stream>>>(x, xb, deg, n128, n);
    k_wprep<<<128, 256, 0, stream>>>(W1, W2, wb);
    k_count<<<(E + 255) / 256, 256, 0, stream>>>(ei, deg, E);
    k_scan<<<1, SCAN_T, 0, stream>>>(deg, offs, cursor, n);
    k_fill<<<(E + n + 255) / 256, 256, 0, stream>>>(ei, cursor, ssrc, E, n);
    k_gemm<<<(n + 63) / 64, 256, 0, stream>>>(xb, wb, h1b, h2b, n);
    k_logits<<<(n * 8 + 255) / 256, 256, 0, stream>>>(h1b, h2b, as1, ad1, as2, ad2,
                                                      es1, ed1, es2, ed2, n);
    k_agg<<<(n + 3) / 4, 256, 0, stream>>>(offs, ssrc, h1b, h2b, es1, ed1, es2, ed2,
                                           b1, b2, gW, gb, x, gamma, beta, out, n);
}

// Round 2
// 360.281 us; speedup vs baseline: 1.3611x; 1.3611x over previous
//
#include <hip/hip_runtime.h>
#include <hip/hip_bf16.h>

// GraphAttentionEncoder: 2x GATConv (shared edges) + gated mix + residual + LN
// N=50000, DIM=128, H=4, C=32, E=800000 (+N self loops)
//
// R1 changes vs R0:
//  - k_agg: direct exp (logits bounded |e|<~2 -> max-subtraction unnecessary);
//    4 exps/edge instead of 8, no serial rescale chain.
//  - h1/h2 interleaved into hb[node][256] (one 512B gather region per edge).
//  - es/ed merged into per-node 32B rows (es[node][8], ed[node][8]).
//  - scan: single-block strided loops (uncoalesced, 1 CU) -> 3-kernel coalesced
//    block scan.
//  - k_gemm: no LDS, no syncthreads. A loaded fp32->bf16 in-register (xb and
//    k_xprep deleted); B frags direct from L2-resident 64KB wb.
//  - k_logits: uint4 vector loads.

typedef unsigned short u16;
typedef __bf16 bf16x8 __attribute__((ext_vector_type(8)));
typedef u16 u16x8 __attribute__((ext_vector_type(8)));
typedef float f32x4 __attribute__((ext_vector_type(4)));

#define LRELU_SLOPE 0.2f
#define LN_EPS 1e-5f

__device__ __forceinline__ float bf2f(u16 u) {
    union { unsigned int i; float f; } v; v.i = ((unsigned int)u) << 16; return v.f;
}
__device__ __forceinline__ u16 f2bf(float f) {
    union { float f; unsigned int i; } v; v.f = f;
    unsigned int lsb = (v.i >> 16) & 1u;
    v.i += 0x7FFFu + lsb;                 // round-to-nearest-even
    return (u16)(v.i >> 16);
}

union U8 { u16x8 u; bf16x8 b; };

// wb[col][k] = W[k][col] bf16 (col 0-127 -> W1, 128-255 -> W2); deg[i]=1 (self loop)
__global__ void k_prep(const float* __restrict__ W1, const float* __restrict__ W2,
                       u16* __restrict__ wb, int* __restrict__ deg, int n) {
    int i = blockIdx.x * 256 + threadIdx.x;
    if (i < 32768) {
        int col = i >> 7, k = i & 127;
        float v = (col < 128) ? W1[k * 128 + col] : W2[k * 128 + (col - 128)];
        wb[i] = f2bf(v);
    }
    if (i < n) deg[i] = 1;
}

__global__ void k_count(const int* __restrict__ ei, int* __restrict__ deg, int E) {
    int i = blockIdx.x * 256 + threadIdx.x;
    if (i < E) atomicAdd(&deg[ei[E + i]], 1);
}

// coalesced 3-phase scan: block sums -> scan of block sums -> per-element offsets
__global__ void k_scan1(const int* __restrict__ deg, int* __restrict__ bsum, int n) {
    __shared__ int s[256];
    int i = blockIdx.x * 256 + threadIdx.x;
    s[threadIdx.x] = (i < n) ? deg[i] : 0;
    __syncthreads();
    for (int o = 128; o; o >>= 1) {
        if (threadIdx.x < o) s[threadIdx.x] += s[threadIdx.x + o];
        __syncthreads();
    }
    if (threadIdx.x == 0) bsum[blockIdx.x] = s[0];
}

__global__ void k_scan2(const int* __restrict__ bsum, int* __restrict__ bpre,
                        int* __restrict__ offs, int nb, int n) {
    __shared__ int s[256];
    int t = threadIdx.x;
    int v = (t < nb) ? bsum[t] : 0;
    s[t] = v;
    __syncthreads();
    for (int o = 1; o < 256; o <<= 1) {
        int u = (t >= o) ? s[t - o] : 0;
        __syncthreads();
        s[t] += u;
        __syncthreads();
    }
    bpre[t] = s[t] - v;                   // exclusive
    if (t == 255) offs[n] = s[255];       // total
}

__global__ void k_scan3(const int* __restrict__ deg, const int* __restrict__ bpre,
                        int* __restrict__ offs, int* __restrict__ cursor, int n) {
    __shared__ int s[256];
    int t = threadIdx.x;
    int i = blockIdx.x * 256 + t;
    int v = (i < n) ? deg[i] : 0;
    s[t] = v;
    __syncthreads();
    for (int o = 1; o < 256; o <<= 1) {
        int u = (t >= o) ? s[t - o] : 0;
        __syncthreads();
        s[t] += u;
        __syncthreads();
    }
    if (i < n) {
        int e = bpre[blockIdx.x] + s[t] - v;
        offs[i] = e;
        cursor[i] = e;
    }
}

__global__ void k_fill(const int* __restrict__ ei, int* __restrict__ cursor,
                       int* __restrict__ ssrc, int E, int n) {
    int i = blockIdx.x * 256 + threadIdx.x;
    if (i >= E + n) return;
    int s, d;
    if (i < E) { s = ei[i]; d = ei[E + i]; } else { s = i - E; d = s; }
    int pos = atomicAdd(&cursor[d], 1);
    ssrc[pos] = s;
}

// MFMA GEMM, no LDS: A = x (fp32->bf16 in-register), B^T = wb (L2-resident 64KB).
// Block = 64 rows (4 waves x 16). Each wave: all 16 col-tiles, K=128 in 4 steps.
// m97 B^T fragment pattern (verified R0): C/D col=lane&15, row=quad*4+reg.
__global__ __launch_bounds__(256) void k_gemm(const float* __restrict__ x,
                                              const u16* __restrict__ wb,
                                              u16* __restrict__ hb, int n) {
    int wave = threadIdx.x >> 6, lane = threadIdx.x & 63;
    int quad = lane >> 4, r16 = lane & 15;
    int row = blockIdx.x * 64 + wave * 16 + r16;
    int arow = (row < n) ? row : n - 1;
    const float* xp = x + (size_t)arow * 128 + quad * 8;
    bf16x8 a[4];
#pragma unroll
    for (int ks = 0; ks < 4; ks++) {
        float4 lo = *(const float4*)(xp + ks * 32);
        float4 hi = *(const float4*)(xp + ks * 32 + 4);
        U8 r;
        r.u[0] = f2bf(lo.x); r.u[1] = f2bf(lo.y); r.u[2] = f2bf(lo.z); r.u[3] = f2bf(lo.w);
        r.u[4] = f2bf(hi.x); r.u[5] = f2bf(hi.y); r.u[6] = f2bf(hi.z); r.u[7] = f2bf(hi.w);
        a[ks] = r.b;
    }
    f32x4 acc[16];
#pragma unroll
    for (int t = 0; t < 16; t++) acc[t] = (f32x4){0.f, 0.f, 0.f, 0.f};
    const u16* bbase = wb + r16 * 128 + quad * 8;
#pragma unroll
    for (int t = 0; t < 16; t++) {
        const u16* bp = bbase + t * 2048;      // t*16 rows * 128
#pragma unroll
        for (int ks = 0; ks < 4; ks++) {
            bf16x8 b = *(const bf16x8*)(bp + ks * 32);
            acc[t] = __builtin_amdgcn_mfma_f32_16x16x32_bf16(a[ks], b, acc[t], 0, 0, 0);
        }
    }
    int row0 = blockIdx.x * 64 + wave * 16 + quad * 4;
#pragma unroll
    for (int t = 0; t < 16; t++) {
        int col = t * 16 + r16;                // 0..255 -> hb interleaved [h1|h2]
#pragma unroll
        for (int g = 0; g < 4; g++) {
            int gr = row0 + g;
            if (gr < n) hb[(size_t)gr * 256 + col] = f2bf(acc[t][g]);
        }
    }
}

// per-(node, layer, head) att dots; thread i -> node=i>>3, slot=i&7 (layer*4+head)
__global__ void k_logits(const u16* __restrict__ hmat,
                         const float* __restrict__ as1, const float* __restrict__ ad1,
                         const float* __restrict__ as2, const float* __restrict__ ad2,
                         float* __restrict__ es, float* __restrict__ ed, int n) {
    int i = blockIdx.x * 256 + threadIdx.x;
    if (i >= n * 8) return;
    int node = i >> 3, slot = i & 7;
    int layer = slot >> 2, head = slot & 3;
    const uint4* hv = (const uint4*)(hmat + (size_t)node * 256 + slot * 32);
    const float* ap = (layer ? as2 : as1) + head * 32;
    const float* dp = (layer ? ad2 : ad1) + head * 32;
    float s = 0.f, d = 0.f;
#pragma unroll
    for (int q = 0; q < 4; q++) {
        uint4 w = hv[q];
        unsigned int ws[4] = {w.x, w.y, w.z, w.w};
#pragma unroll
        for (int h = 0; h < 4; h++) {
            float v0 = bf2f((u16)(ws[h] & 0xFFFF));
            float v1 = bf2f((u16)(ws[h] >> 16));
            int c = q * 8 + h * 2;
            s += v0 * ap[c] + v1 * ap[c + 1];
            d += v0 * dp[c] + v1 * dp[c + 1];
        }
    }
    es[i] = s;
    ed[i] = d;
}

__device__ __forceinline__ float wred(float v) {
#pragma unroll
    for (int off = 32; off; off >>= 1) v += __shfl_xor(v, off, 64);
    return v;
}

// one wave per node: direct-exp softmax aggregation for both layers,
// then bias -> gate softmax -> residual -> LayerNorm
__global__ __launch_bounds__(256) void k_agg(
    const int* __restrict__ offs, const int* __restrict__ ssrc,
    const u16* __restrict__ hmat,
    const float* __restrict__ es, const float* __restrict__ ed,
    const float* __restrict__ b1, const float* __restrict__ b2,
    const float* __restrict__ gW, const float* __restrict__ gb,
    const float* __restrict__ x, const float* __restrict__ gamma,
    const float* __restrict__ beta, float* __restrict__ out, int n) {
    int wave = threadIdx.x >> 6, lane = threadIdx.x & 63;
    int node = blockIdx.x * 4 + wave;
    if (node >= n) return;

    int ha = lane >> 5;       // head for col = lane       (layer half a)
    int hc = 2 + ha;          // head for col = 64+lane    (layer half b)
    const float* edp = ed + node * 8;
    float ed1a = edp[ha], ed1b = edp[hc], ed2a = edp[4 + ha], ed2b = edp[4 + hc];

    float l1a = 0.f, l1b = 0.f, l2a = 0.f, l2b = 0.f;
    float a1a = 0.f, a1b = 0.f, a2a = 0.f, a2b = 0.f;

    int beg = offs[node], end = offs[node + 1];
    for (int k = beg; k < end; k++) {
        int j = ssrc[k];
        const float* ep = es + j * 8;
        const u16* hr = hmat + (size_t)j * 256;
        float e1a = ep[ha] + ed1a;
        float e1b = ep[hc] + ed1b;
        float e2a = ep[4 + ha] + ed2a;
        float e2b = ep[4 + hc] + ed2b;
        e1a = (e1a > 0.f) ? e1a : LRELU_SLOPE * e1a;
        e1b = (e1b > 0.f) ? e1b : LRELU_SLOPE * e1b;
        e2a = (e2a > 0.f) ? e2a : LRELU_SLOPE * e2a;
        e2b = (e2b > 0.f) ? e2b : LRELU_SLOPE * e2b;
        float p1a = __expf(e1a), p1b = __expf(e1b);
        float p2a = __expf(e2a), p2b = __expf(e2b);
        float v1a = bf2f(hr[lane]);
        float v1b = bf2f(hr[64 + lane]);
        float v2a = bf2f(hr[128 + lane]);
        float v2b = bf2f(hr[192 + lane]);
        l1a += p1a; a1a += p1a * v1a;
        l1b += p1b; a1b += p1b * v1b;
        l2a += p2a; a2a += p2a * v2a;
        l2b += p2b; a2b += p2b * v2b;
    }

    float o1a = a1a / l1a + b1[lane];
    float o1b = a1b / l1b + b1[64 + lane];
    float o2a = a2a / l2a + b2[lane];
    float o2b = a2b / l2b + b2[64 + lane];

    // gate logits: concat(out1,out2) @ gate_W(256x2) + gate_b
    float p0 = o1a * gW[2 * lane] + o1b * gW[2 * (64 + lane)] +
               o2a * gW[2 * (128 + lane)] + o2b * gW[2 * (192 + lane)];
    float p1 = o1a * gW[2 * lane + 1] + o1b * gW[2 * (64 + lane) + 1] +
               o2a * gW[2 * (128 + lane) + 1] + o2b * gW[2 * (192 + lane) + 1];
    p0 = wred(p0) + gb[0];
    p1 = wred(p1) + gb[1];
    float mg = fmaxf(p0, p1);
    float eg0 = __expf(p0 - mg), eg1 = __expf(p1 - mg);
    float g0 = eg0 / (eg0 + eg1), g1 = 1.f - g0;

    float ya = x[(size_t)node * 128 + lane] + g0 * o1a + g1 * o2a;
    float yb = x[(size_t)node * 128 + 64 + lane] + g0 * o1b + g1 * o2b;

    float s  = wred(ya + yb);
    float ss = wred(ya * ya + yb * yb);
    float mean = s * (1.f / 128.f);
    float var  = ss * (1.f / 128.f) - mean * mean;
    float rstd = rsqrtf(var + LN_EPS);
    out[(size_t)node * 128 + lane]      = (ya - mean) * rstd * gamma[lane] + beta[lane];
    out[(size_t)node * 128 + 64 + lane] = (yb - mean) * rstd * gamma[64 + lane] + beta[64 + lane];
}

extern "C" void kernel_launch(void* const* d_in, const int* in_sizes, int n_in,
                              void* d_out, int out_size, void* d_ws, size_t ws_size,
                              hipStream_t stream) {
    const float* x   = (const float*)d_in[0];
    const int*   ei  = (const int*)d_in[1];
    const float* W1  = (const float*)d_in[2];
    const float* b1  = (const float*)d_in[3];
    const float* as1 = (const float*)d_in[4];
    const float* ad1 = (const float*)d_in[5];
    const float* W2  = (const float*)d_in[6];
    const float* b2  = (const float*)d_in[7];
    const float* as2 = (const float*)d_in[8];
    const float* ad2 = (const float*)d_in[9];
    const float* gW  = (const float*)d_in[10];
    const float* gb  = (const float*)d_in[11];
    const float* gamma = (const float*)d_in[12];
    const float* beta  = (const float*)d_in[13];
    float* out = (float*)d_out;

    int n = in_sizes[0] / 128;
    int E = in_sizes[1] / 2;

    char* p = (char*)d_ws;
    auto take = [&](size_t bytes) {
        char* q = p;
        p += (bytes + 255) & ~(size_t)255;
        return (void*)q;
    };
    u16* wb    = (u16*)take((size_t)256 * 128 * 2);
    u16* hb    = (u16*)take((size_t)n * 256 * 2);
    float* es  = (float*)take((size_t)n * 8 * 4);
    float* ed  = (float*)take((size_t)n * 8 * 4);
    int* deg    = (int*)take((size_t)n * 4);
    int* offs   = (int*)take((size_t)(n + 1) * 4);
    int* cursor = (int*)take((size_t)n * 4);
    int* bsum   = (int*)take((size_t)256 * 4);
    int* bpre   = (int*)take((size_t)256 * 4);
    int* ssrc   = (int*)take((size_t)(E + n) * 4);

    int nb = (n + 255) / 256;   // 196 (must be <= 256 for k_scan2)

    k_prep<<<nb, 256, 0, stream>>>(W1, W2, wb, deg, n);
    k_count<<<(E + 255) / 256, 256, 0, stream>>>(ei, deg, E);
    k_scan1<<<nb, 256, 0, stream>>>(deg, bsum, n);
    k_scan2<<<1, 256, 0, stream>>>(bsum, bpre, offs, nb, n);
    k_scan3<<<nb, 256, 0, stream>>>(deg, bpre, offs, cursor, n);
    k_fill<<<(E + n + 255) / 256, 256, 0, stream>>>(ei, cursor, ssrc, E, n);
    k_gemm<<<(n + 63) / 64, 256, 0, stream>>>(x, wb, hb, n);
    k_logits<<<(n * 8 + 255) / 256, 256, 0, stream>>>(hb, as1, ad1, as2, ad2, es, ed, n);
    k_agg<<<(n + 3) / 4, 256, 0, stream>>>(offs, ssrc, hb, es, ed,
                                           b1, b2, gW, gb, x, gamma, beta, out, n);
}

// Round 3
// 340.499 us; speedup vs baseline: 1.4402x; 1.0581x over previous
//
#include <hip/hip_runtime.h>
#include <hip/hip_bf16.h>

// GraphAttentionEncoder: 2x GATConv (shared edges) + gated mix + residual + LN
// N=50000, DIM=128, H=4, C=32, E=800000 (+N self loops)
//
// R2 changes vs R1:
//  - per-edge softmax weights precomputed (bf16, packed layer1|layer2 per head,
//    16B/edge) inside the counting-sort fill kernel; k_agg inner loop is now
//    3 loads + ~21 VALU per edge.
//  - hb packed: hbp[node][128] uint, lo16=h1 col, hi16=h2 col. k_agg lane owns
//    cols (2*lane, 2*lane+1) -> single uint2 gather covers the whole row.
//  - scan2 merged into scan3 (each block redundantly scans the 196 block sums).

typedef unsigned short u16;
typedef __bf16 bf16x8 __attribute__((ext_vector_type(8)));
typedef float f32x4 __attribute__((ext_vector_type(4)));

#define LRELU_SLOPE 0.2f
#define LN_EPS 1e-5f

__device__ __forceinline__ float bfbits(unsigned int hi_bits) {
    union { unsigned int i; float f; } v; v.i = hi_bits; return v.f;
}
__device__ __forceinline__ float bflo(unsigned int u) { return bfbits(u << 16); }
__device__ __forceinline__ float bfhi(unsigned int u) { return bfbits(u & 0xFFFF0000u); }
__device__ __forceinline__ u16 f2bf(float f) {
    union { float f; unsigned int i; } v; v.f = f;
    unsigned int lsb = (v.i >> 16) & 1u;
    v.i += 0x7FFFu + lsb;                 // round-to-nearest-even
    return (u16)(v.i >> 16);
}

// wb[col][k] = W[k][col] bf16 (col 0-127 -> W1, 128-255 -> W2); deg[i]=1
__global__ void k_prep(const float* __restrict__ W1, const float* __restrict__ W2,
                       u16* __restrict__ wb, int* __restrict__ deg, int n) {
    int i = blockIdx.x * 256 + threadIdx.x;
    if (i < 32768) {
        int col = i >> 7, k = i & 127;
        float v = (col < 128) ? W1[k * 128 + col] : W2[k * 128 + (col - 128)];
        wb[i] = f2bf(v);
    }
    if (i < n) deg[i] = 1;
}

__global__ void k_count(const int* __restrict__ ei, int* __restrict__ deg, int E) {
    int i = blockIdx.x * 256 + threadIdx.x;
    if (i < E) atomicAdd(&deg[ei[E + i]], 1);
}

__global__ void k_bsum(const int* __restrict__ deg, int* __restrict__ bsum, int n) {
    __shared__ int s[256];
    int i = blockIdx.x * 256 + threadIdx.x;
    s[threadIdx.x] = (i < n) ? deg[i] : 0;
    __syncthreads();
    for (int o = 128; o; o >>= 1) {
        if (threadIdx.x < o) s[threadIdx.x] += s[threadIdx.x + o];
        __syncthreads();
    }
    if (threadIdx.x == 0) bsum[blockIdx.x] = s[0];
}

// each block: redundant scan of bsum[0..nb) for its prefix, then local scan
__global__ void k_scan(const int* __restrict__ deg, const int* __restrict__ bsum,
                       int* __restrict__ offs, int* __restrict__ cursor,
                       int nb, int n) {
    __shared__ int s[256];
    __shared__ int bp;
    int t = threadIdx.x;
    int bv = (t < nb) ? bsum[t] : 0;
    s[t] = bv;
    __syncthreads();
    for (int o = 1; o < 256; o <<= 1) {
        int u = (t >= o) ? s[t - o] : 0;
        __syncthreads();
        s[t] += u;
        __syncthreads();
    }
    if (t == (int)blockIdx.x) bp = s[t] - bv;   // exclusive prefix of this block
    __syncthreads();
    int i = blockIdx.x * 256 + t;
    int v = (i < n) ? deg[i] : 0;
    s[t] = v;
    __syncthreads();
    for (int o = 1; o < 256; o <<= 1) {
        int u = (t >= o) ? s[t - o] : 0;
        __syncthreads();
        s[t] += u;
        __syncthreads();
    }
    if (i < n) {
        int e = bp + s[t] - v;
        offs[i] = e;
        cursor[i] = e;
        if (i == n - 1) offs[n] = e + v;
    }
}

// MFMA GEMM, no LDS. Output packed: hbp[row][c] = (h2[c]<<16)|h1[c], c in [0,128)
__global__ __launch_bounds__(256) void k_gemm(const float* __restrict__ x,
                                              const u16* __restrict__ wb,
                                              unsigned int* __restrict__ hbp, int n) {
    int wave = threadIdx.x >> 6, lane = threadIdx.x & 63;
    int quad = lane >> 4, r16 = lane & 15;
    int row = blockIdx.x * 64 + wave * 16 + r16;
    int arow = (row < n) ? row : n - 1;
    const float* xp = x + (size_t)arow * 128 + quad * 8;
    union { u16 u[8]; bf16x8 b; } ar;
    bf16x8 a[4];
#pragma unroll
    for (int ks = 0; ks < 4; ks++) {
        float4 lo = *(const float4*)(xp + ks * 32);
        float4 hi = *(const float4*)(xp + ks * 32 + 4);
        ar.u[0] = f2bf(lo.x); ar.u[1] = f2bf(lo.y); ar.u[2] = f2bf(lo.z); ar.u[3] = f2bf(lo.w);
        ar.u[4] = f2bf(hi.x); ar.u[5] = f2bf(hi.y); ar.u[6] = f2bf(hi.z); ar.u[7] = f2bf(hi.w);
        a[ks] = ar.b;
    }
    f32x4 acc[16];
#pragma unroll
    for (int t = 0; t < 16; t++) acc[t] = (f32x4){0.f, 0.f, 0.f, 0.f};
    const u16* bbase = wb + r16 * 128 + quad * 8;
#pragma unroll
    for (int t = 0; t < 16; t++) {
        const u16* bp = bbase + t * 2048;      // t*16 rows * 128
#pragma unroll
        for (int ks = 0; ks < 4; ks++) {
            bf16x8 b = *(const bf16x8*)(bp + ks * 32);
            acc[t] = __builtin_amdgcn_mfma_f32_16x16x32_bf16(a[ks], b, acc[t], 0, 0, 0);
        }
    }
    int row0 = blockIdx.x * 64 + wave * 16 + quad * 4;
#pragma unroll
    for (int t = 0; t < 8; t++) {
        int c = t * 16 + r16;                  // packed col 0..127
#pragma unroll
        for (int g = 0; g < 4; g++) {
            int gr = row0 + g;
            if (gr < n) {
                unsigned int pv = ((unsigned int)f2bf(acc[t + 8][g]) << 16) | f2bf(acc[t][g]);
                hbp[(size_t)gr * 128 + c] = pv;
            }
        }
    }
}

// thread per (node, head): both layers from packed row.
// es/ed rows: [node][8], slot = layer*4 + head
__global__ void k_logits(const unsigned int* __restrict__ hbp,
                         const float* __restrict__ as1, const float* __restrict__ ad1,
                         const float* __restrict__ as2, const float* __restrict__ ad2,
                         float* __restrict__ es, float* __restrict__ ed, int n) {
    int i = blockIdx.x * 256 + threadIdx.x;
    if (i >= n * 4) return;
    int node = i >> 2, head = i & 3;
    const uint4* hv = (const uint4*)(hbp + (size_t)node * 128 + head * 32);
    const float* a1 = as1 + head * 32;
    const float* d1 = ad1 + head * 32;
    const float* a2 = as2 + head * 32;
    const float* d2 = ad2 + head * 32;
    float s1 = 0.f, t1 = 0.f, s2 = 0.f, t2 = 0.f;
#pragma unroll
    for (int q = 0; q < 8; q++) {
        uint4 w = hv[q];
        unsigned int ws[4] = {w.x, w.y, w.z, w.w};
#pragma unroll
        for (int h = 0; h < 4; h++) {
            int c = q * 4 + h;
            float v1 = bflo(ws[h]), v2 = bfhi(ws[h]);
            s1 += v1 * a1[c]; t1 += v1 * d1[c];
            s2 += v2 * a2[c]; t2 += v2 * d2[c];
        }
    }
    es[node * 8 + head]     = s1;
    ed[node * 8 + head]     = t1;
    es[node * 8 + 4 + head] = s2;
    ed[node * 8 + 4 + head] = t2;
}

// counting sort + per-edge weight computation fused.
// w[pos][h] = (bf16(exp(lrelu(e2)))<<16) | bf16(exp(lrelu(e1))), h in [0,4)
__global__ void k_fill(const int* __restrict__ ei, int* __restrict__ cursor,
                       const float* __restrict__ es, const float* __restrict__ ed,
                       int* __restrict__ ssrc, uint4* __restrict__ w, int E, int n) {
    int i = blockIdx.x * 256 + threadIdx.x;
    if (i >= E + n) return;
    int s, d;
    if (i < E) { s = ei[i]; d = ei[E + i]; } else { s = i - E; d = s; }
    int pos = atomicAdd(&cursor[d], 1);
    ssrc[pos] = s;
    float4 eslo = *(const float4*)(es + s * 8);
    float4 eshi = *(const float4*)(es + s * 8 + 4);
    float4 edlo = *(const float4*)(ed + d * 8);
    float4 edhi = *(const float4*)(ed + d * 8 + 4);
    float e1[4] = {eslo.x + edlo.x, eslo.y + edlo.y, eslo.z + edlo.z, eslo.w + edlo.w};
    float e2[4] = {eshi.x + edhi.x, eshi.y + edhi.y, eshi.z + edhi.z, eshi.w + edhi.w};
    unsigned int uw[4];
#pragma unroll
    for (int h = 0; h < 4; h++) {
        float a = e1[h]; a = (a > 0.f) ? a : LRELU_SLOPE * a;
        float b = e2[h]; b = (b > 0.f) ? b : LRELU_SLOPE * b;
        uw[h] = ((unsigned int)f2bf(__expf(b)) << 16) | f2bf(__expf(a));
    }
    w[pos] = make_uint4(uw[0], uw[1], uw[2], uw[3]);
}

__device__ __forceinline__ float wred(float v) {
#pragma unroll
    for (int off = 32; off; off >>= 1) v += __shfl_xor(v, off, 64);
    return v;
}

// one wave per node; lane owns packed cols ca=2*lane, cb=2*lane+1 (same head)
__global__ __launch_bounds__(256) void k_agg(
    const int* __restrict__ offs, const int* __restrict__ ssrc,
    const unsigned int* __restrict__ hbp, const unsigned int* __restrict__ w,
    const float* __restrict__ b1, const float* __restrict__ b2,
    const float* __restrict__ gW, const float* __restrict__ gb,
    const float* __restrict__ x, const float* __restrict__ gamma,
    const float* __restrict__ beta, float* __restrict__ out, int n) {
    int wave = threadIdx.x >> 6, lane = threadIdx.x & 63;
    int node = blockIdx.x * 4 + wave;
    if (node >= n) return;

    int ca = lane * 2, cb = ca + 1;
    int head = lane >> 4;                  // = ca>>5

    float l1 = 0.f, l2 = 0.f;
    float a1a = 0.f, a1b = 0.f, a2a = 0.f, a2b = 0.f;

    int beg = offs[node], end = offs[node + 1];
    for (int k = beg; k < end; k++) {
        int j = ssrc[k];
        unsigned int wp = w[(size_t)k * 4 + head];
        uint2 q = *(const uint2*)(hbp + (size_t)j * 128 + ca);
        float w1 = bflo(wp), w2 = bfhi(wp);
        float v1a = bflo(q.x), v2a = bfhi(q.x);
        float v1b = bflo(q.y), v2b = bfhi(q.y);
        l1 += w1; l2 += w2;
        a1a += w1 * v1a; a1b += w1 * v1b;
        a2a += w2 * v2a; a2b += w2 * v2b;
    }

    float2 b1v = *(const float2*)(b1 + ca);
    float2 b2v = *(const float2*)(b2 + ca);
    float r1 = 1.f / l1, r2 = 1.f / l2;
    float o1a = a1a * r1 + b1v.x;
    float o1b = a1b * r1 + b1v.y;
    float o2a = a2a * r2 + b2v.x;
    float o2b = a2b * r2 + b2v.y;

    // gate logits: concat(out1,out2) @ gate_W(256x2) + gate_b
    float2 g1a = *(const float2*)(gW + 2 * ca);          // rows ca,cb
    float2 g1b = *(const float2*)(gW + 2 * cb);
    float2 g2a = *(const float2*)(gW + 2 * (128 + ca));
    float2 g2b = *(const float2*)(gW + 2 * (128 + cb));
    float p0 = o1a * g1a.x + o1b * g1b.x + o2a * g2a.x + o2b * g2b.x;
    float p1 = o1a * g1a.y + o1b * g1b.y + o2a * g2a.y + o2b * g2b.y;
    p0 = wred(p0) + gb[0];
    p1 = wred(p1) + gb[1];
    float mg = fmaxf(p0, p1);
    float eg0 = __expf(p0 - mg), eg1 = __expf(p1 - mg);
    float g0 = eg0 / (eg0 + eg1), g1 = 1.f - g0;

    float2 xv = *(const float2*)(x + (size_t)node * 128 + ca);
    float ya = xv.x + g0 * o1a + g1 * o2a;
    float yb = xv.y + g0 * o1b + g1 * o2b;

    float s  = wred(ya + yb);
    float ss = wred(ya * ya + yb * yb);
    float mean = s * (1.f / 128.f);
    float var  = ss * (1.f / 128.f) - mean * mean;
    float rstd = rsqrtf(var + LN_EPS);
    float2 gv = *(const float2*)(gamma + ca);
    float2 bv = *(const float2*)(beta + ca);
    float2 ov;
    ov.x = (ya - mean) * rstd * gv.x + bv.x;
    ov.y = (yb - mean) * rstd * gv.y + bv.y;
    *(float2*)(out + (size_t)node * 128 + ca) = ov;
}

extern "C" void kernel_launch(void* const* d_in, const int* in_sizes, int n_in,
                              void* d_out, int out_size, void* d_ws, size_t ws_size,
                              hipStream_t stream) {
    const float* x   = (const float*)d_in[0];
    const int*   ei  = (const int*)d_in[1];
    const float* W1  = (const float*)d_in[2];
    const float* b1  = (const float*)d_in[3];
    const float* as1 = (const float*)d_in[4];
    const float* ad1 = (const float*)d_in[5];
    const float* W2  = (const float*)d_in[6];
    const float* b2  = (const float*)d_in[7];
    const float* as2 = (const float*)d_in[8];
    const float* ad2 = (const float*)d_in[9];
    const float* gW  = (const float*)d_in[10];
    const float* gb  = (const float*)d_in[11];
    const float* gamma = (const float*)d_in[12];
    const float* beta  = (const float*)d_in[13];
    float* out = (float*)d_out;

    int n = in_sizes[0] / 128;
    int E = in_sizes[1] / 2;

    char* p = (char*)d_ws;
    auto take = [&](size_t bytes) {
        char* q = p;
        p += (bytes + 255) & ~(size_t)255;
        return (void*)q;
    };
    u16* wb    = (u16*)take((size_t)256 * 128 * 2);
    unsigned int* hbp = (unsigned int*)take((size_t)n * 128 * 4);
    float* es  = (float*)take((size_t)n * 8 * 4);
    float* ed  = (float*)take((size_t)n * 8 * 4);
    int* deg    = (int*)take((size_t)n * 4);
    int* offs   = (int*)take((size_t)(n + 1) * 4);
    int* cursor = (int*)take((size_t)n * 4);
    int* bsum   = (int*)take((size_t)256 * 4);
    int* ssrc   = (int*)take((size_t)(E + n) * 4);
    uint4* w    = (uint4*)take((size_t)(E + n) * 16);

    int nb = (n + 255) / 256;   // 196 (<= 256 required by k_scan)

    k_prep<<<nb, 256, 0, stream>>>(W1, W2, wb, deg, n);
    k_count<<<(E + 255) / 256, 256, 0, stream>>>(ei, deg, E);
    k_bsum<<<nb, 256, 0, stream>>>(deg, bsum, n);
    k_scan<<<nb, 256, 0, stream>>>(deg, bsum, offs, cursor, nb, n);
    k_gemm<<<(n + 63) / 64, 256, 0, stream>>>(x, wb, hbp, n);
    k_logits<<<(n * 4 + 255) / 256, 256, 0, stream>>>(hbp, as1, ad1, as2, ad2, es, ed, n);
    k_fill<<<(E + n + 255) / 256, 256, 0, stream>>>(ei, cursor, es, ed, ssrc, w, E, n);
    k_agg<<<(n + 3) / 4, 256, 0, stream>>>(offs, ssrc, hbp, (const unsigned int*)w,
                                           b1, b2, gW, gb, x, gamma, beta, out, n);
}

// Round 4
// 305.828 us; speedup vs baseline: 1.6034x; 1.1134x over previous
//
#include <hip/hip_runtime.h>
#include <hip/hip_bf16.h>

// GraphAttentionEncoder: 2x GATConv (shared edges) + gated mix + residual + LN
// N=50000, DIM=128, H=4, C=32, E=800000 (+N self loops)
//
// R3 changes vs R2 (k_agg only — isolate the latency fix):
//  - inner loop unrolled x4: 4 independent hbp gathers in flight per wave
//    (was 1: dependent chain ssrc->gather->fma left the memory pipe idle;
//    R2 counters showed nothing saturated = latency-bound).
//  - node made wave-uniform via readfirstlane -> offs/ssrc/w loads scalarize
//    (s_load, scalar cache); per-edge weight selected from SGPRs by head.

typedef unsigned short u16;
typedef __bf16 bf16x8 __attribute__((ext_vector_type(8)));
typedef float f32x4 __attribute__((ext_vector_type(4)));

#define LRELU_SLOPE 0.2f
#define LN_EPS 1e-5f

__device__ __forceinline__ float bfbits(unsigned int hi_bits) {
    union { unsigned int i; float f; } v; v.i = hi_bits; return v.f;
}
__device__ __forceinline__ float bflo(unsigned int u) { return bfbits(u << 16); }
__device__ __forceinline__ float bfhi(unsigned int u) { return bfbits(u & 0xFFFF0000u); }
__device__ __forceinline__ u16 f2bf(float f) {
    union { float f; unsigned int i; } v; v.f = f;
    unsigned int lsb = (v.i >> 16) & 1u;
    v.i += 0x7FFFu + lsb;                 // round-to-nearest-even
    return (u16)(v.i >> 16);
}

// wb[col][k] = W[k][col] bf16 (col 0-127 -> W1, 128-255 -> W2); deg[i]=1
__global__ void k_prep(const float* __restrict__ W1, const float* __restrict__ W2,
                       u16* __restrict__ wb, int* __restrict__ deg, int n) {
    int i = blockIdx.x * 256 + threadIdx.x;
    if (i < 32768) {
        int col = i >> 7, k = i & 127;
        float v = (col < 128) ? W1[k * 128 + col] : W2[k * 128 + (col - 128)];
        wb[i] = f2bf(v);
    }
    if (i < n) deg[i] = 1;
}

__global__ void k_count(const int* __restrict__ ei, int* __restrict__ deg, int E) {
    int i = blockIdx.x * 256 + threadIdx.x;
    if (i < E) atomicAdd(&deg[ei[E + i]], 1);
}

__global__ void k_bsum(const int* __restrict__ deg, int* __restrict__ bsum, int n) {
    __shared__ int s[256];
    int i = blockIdx.x * 256 + threadIdx.x;
    s[threadIdx.x] = (i < n) ? deg[i] : 0;
    __syncthreads();
    for (int o = 128; o; o >>= 1) {
        if (threadIdx.x < o) s[threadIdx.x] += s[threadIdx.x + o];
        __syncthreads();
    }
    if (threadIdx.x == 0) bsum[blockIdx.x] = s[0];
}

// each block: redundant scan of bsum[0..nb) for its prefix, then local scan
__global__ void k_scan(const int* __restrict__ deg, const int* __restrict__ bsum,
                       int* __restrict__ offs, int* __restrict__ cursor,
                       int nb, int n) {
    __shared__ int s[256];
    __shared__ int bp;
    int t = threadIdx.x;
    int bv = (t < nb) ? bsum[t] : 0;
    s[t] = bv;
    __syncthreads();
    for (int o = 1; o < 256; o <<= 1) {
        int u = (t >= o) ? s[t - o] : 0;
        __syncthreads();
        s[t] += u;
        __syncthreads();
    }
    if (t == (int)blockIdx.x) bp = s[t] - bv;   // exclusive prefix of this block
    __syncthreads();
    int i = blockIdx.x * 256 + t;
    int v = (i < n) ? deg[i] : 0;
    s[t] = v;
    __syncthreads();
    for (int o = 1; o < 256; o <<= 1) {
        int u = (t >= o) ? s[t - o] : 0;
        __syncthreads();
        s[t] += u;
        __syncthreads();
    }
    if (i < n) {
        int e = bp + s[t] - v;
        offs[i] = e;
        cursor[i] = e;
        if (i == n - 1) offs[n] = e + v;
    }
}

// MFMA GEMM, no LDS. Output packed: hbp[row][c] = (h2[c]<<16)|h1[c], c in [0,128)
__global__ __launch_bounds__(256) void k_gemm(const float* __restrict__ x,
                                              const u16* __restrict__ wb,
                                              unsigned int* __restrict__ hbp, int n) {
    int wave = threadIdx.x >> 6, lane = threadIdx.x & 63;
    int quad = lane >> 4, r16 = lane & 15;
    int row = blockIdx.x * 64 + wave * 16 + r16;
    int arow = (row < n) ? row : n - 1;
    const float* xp = x + (size_t)arow * 128 + quad * 8;
    union { u16 u[8]; bf16x8 b; } ar;
    bf16x8 a[4];
#pragma unroll
    for (int ks = 0; ks < 4; ks++) {
        float4 lo = *(const float4*)(xp + ks * 32);
        float4 hi = *(const float4*)(xp + ks * 32 + 4);
        ar.u[0] = f2bf(lo.x); ar.u[1] = f2bf(lo.y); ar.u[2] = f2bf(lo.z); ar.u[3] = f2bf(lo.w);
        ar.u[4] = f2bf(hi.x); ar.u[5] = f2bf(hi.y); ar.u[6] = f2bf(hi.z); ar.u[7] = f2bf(hi.w);
        a[ks] = ar.b;
    }
    f32x4 acc[16];
#pragma unroll
    for (int t = 0; t < 16; t++) acc[t] = (f32x4){0.f, 0.f, 0.f, 0.f};
    const u16* bbase = wb + r16 * 128 + quad * 8;
#pragma unroll
    for (int t = 0; t < 16; t++) {
        const u16* bp = bbase + t * 2048;      // t*16 rows * 128
#pragma unroll
        for (int ks = 0; ks < 4; ks++) {
            bf16x8 b = *(const bf16x8*)(bp + ks * 32);
            acc[t] = __builtin_amdgcn_mfma_f32_16x16x32_bf16(a[ks], b, acc[t], 0, 0, 0);
        }
    }
    int row0 = blockIdx.x * 64 + wave * 16 + quad * 4;
#pragma unroll
    for (int t = 0; t < 8; t++) {
        int c = t * 16 + r16;                  // packed col 0..127
#pragma unroll
        for (int g = 0; g < 4; g++) {
            int gr = row0 + g;
            if (gr < n) {
                unsigned int pv = ((unsigned int)f2bf(acc[t + 8][g]) << 16) | f2bf(acc[t][g]);
                hbp[(size_t)gr * 128 + c] = pv;
            }
        }
    }
}

// thread per (node, head): both layers from packed row.
// es/ed rows: [node][8], slot = layer*4 + head
__global__ void k_logits(const unsigned int* __restrict__ hbp,
                         const float* __restrict__ as1, const float* __restrict__ ad1,
                         const float* __restrict__ as2, const float* __restrict__ ad2,
                         float* __restrict__ es, float* __restrict__ ed, int n) {
    int i = blockIdx.x * 256 + threadIdx.x;
    if (i >= n * 4) return;
    int node = i >> 2, head = i & 3;
    const uint4* hv = (const uint4*)(hbp + (size_t)node * 128 + head * 32);
    const float* a1 = as1 + head * 32;
    const float* d1 = ad1 + head * 32;
    const float* a2 = as2 + head * 32;
    const float* d2 = ad2 + head * 32;
    float s1 = 0.f, t1 = 0.f, s2 = 0.f, t2 = 0.f;
#pragma unroll
    for (int q = 0; q < 8; q++) {
        uint4 w = hv[q];
        unsigned int ws[4] = {w.x, w.y, w.z, w.w};
#pragma unroll
        for (int h = 0; h < 4; h++) {
            int c = q * 4 + h;
            float v1 = bflo(ws[h]), v2 = bfhi(ws[h]);
            s1 += v1 * a1[c]; t1 += v1 * d1[c];
            s2 += v2 * a2[c]; t2 += v2 * d2[c];
        }
    }
    es[node * 8 + head]     = s1;
    ed[node * 8 + head]     = t1;
    es[node * 8 + 4 + head] = s2;
    ed[node * 8 + 4 + head] = t2;
}

// counting sort + per-edge weight computation fused.
// w[pos][h] = (bf16(exp(lrelu(e2)))<<16) | bf16(exp(lrelu(e1))), h in [0,4)
__global__ void k_fill(const int* __restrict__ ei, int* __restrict__ cursor,
                       const float* __restrict__ es, const float* __restrict__ ed,
                       int* __restrict__ ssrc, uint4* __restrict__ w, int E, int n) {
    int i = blockIdx.x * 256 + threadIdx.x;
    if (i >= E + n) return;
    int s, d;
    if (i < E) { s = ei[i]; d = ei[E + i]; } else { s = i - E; d = s; }
    int pos = atomicAdd(&cursor[d], 1);
    ssrc[pos] = s;
    float4 eslo = *(const float4*)(es + s * 8);
    float4 eshi = *(const float4*)(es + s * 8 + 4);
    float4 edlo = *(const float4*)(ed + d * 8);
    float4 edhi = *(const float4*)(ed + d * 8 + 4);
    float e1[4] = {eslo.x + edlo.x, eslo.y + edlo.y, eslo.z + edlo.z, eslo.w + edlo.w};
    float e2[4] = {eshi.x + edhi.x, eshi.y + edhi.y, eshi.z + edhi.z, eshi.w + edhi.w};
    unsigned int uw[4];
#pragma unroll
    for (int h = 0; h < 4; h++) {
        float a = e1[h]; a = (a > 0.f) ? a : LRELU_SLOPE * a;
        float b = e2[h]; b = (b > 0.f) ? b : LRELU_SLOPE * b;
        uw[h] = ((unsigned int)f2bf(__expf(b)) << 16) | f2bf(__expf(a));
    }
    w[pos] = make_uint4(uw[0], uw[1], uw[2], uw[3]);
}

__device__ __forceinline__ float wred(float v) {
#pragma unroll
    for (int off = 32; off; off >>= 1) v += __shfl_xor(v, off, 64);
    return v;
}

__device__ __forceinline__ unsigned int hsel(uint4 w, int head) {
    unsigned int r = (head == 0) ? w.x : (head == 1) ? w.y : (head == 2) ? w.z : w.w;
    return r;
}

// one wave per node; lane owns packed cols ca=2*lane, cb=2*lane+1 (same head).
// Inner loop unrolled x4 for memory-level parallelism.
__global__ __launch_bounds__(256) void k_agg(
    const int* __restrict__ offs, const int* __restrict__ ssrc,
    const unsigned int* __restrict__ hbp, const uint4* __restrict__ w4,
    const float* __restrict__ b1, const float* __restrict__ b2,
    const float* __restrict__ gW, const float* __restrict__ gb,
    const float* __restrict__ x, const float* __restrict__ gamma,
    const float* __restrict__ beta, float* __restrict__ out, int n) {
    int wave = threadIdx.x >> 6, lane = threadIdx.x & 63;
    int node = blockIdx.x * 4 + wave;
    if (node >= n) return;
    node = __builtin_amdgcn_readfirstlane(node);   // wave-uniform -> s_loads

    int ca = lane * 2, cb = ca + 1;
    int head = lane >> 4;                  // = ca>>5

    float l1 = 0.f, l2 = 0.f;
    float a1a = 0.f, a1b = 0.f, a2a = 0.f, a2b = 0.f;

    int beg = offs[node], end = offs[node + 1];
    int k = beg;
    for (; k + 3 < end; k += 4) {
        int j0 = ssrc[k], j1 = ssrc[k + 1], j2 = ssrc[k + 2], j3 = ssrc[k + 3];
        uint4 w0 = w4[k], w1v = w4[k + 1], w2v = w4[k + 2], w3v = w4[k + 3];
        uint2 q0 = *(const uint2*)(hbp + (size_t)j0 * 128 + ca);
        uint2 q1 = *(const uint2*)(hbp + (size_t)j1 * 128 + ca);
        uint2 q2 = *(const uint2*)(hbp + (size_t)j2 * 128 + ca);
        uint2 q3 = *(const uint2*)(hbp + (size_t)j3 * 128 + ca);
        unsigned int wp0 = hsel(w0, head), wp1 = hsel(w1v, head);
        unsigned int wp2 = hsel(w2v, head), wp3 = hsel(w3v, head);
#define ACC(wp, q) { \
        float ww1 = bflo(wp), ww2 = bfhi(wp); \
        l1 += ww1; l2 += ww2; \
        a1a += ww1 * bflo(q.x); a1b += ww1 * bflo(q.y); \
        a2a += ww2 * bfhi(q.x); a2b += ww2 * bfhi(q.y); }
        ACC(wp0, q0) ACC(wp1, q1) ACC(wp2, q2) ACC(wp3, q3)
    }
    for (; k < end; k++) {
        int j = ssrc[k];
        uint4 wv = w4[k];
        uint2 q = *(const uint2*)(hbp + (size_t)j * 128 + ca);
        unsigned int wp = hsel(wv, head);
        ACC(wp, q)
    }
#undef ACC

    float2 b1v = *(const float2*)(b1 + ca);
    float2 b2v = *(const float2*)(b2 + ca);
    float r1 = 1.f / l1, r2 = 1.f / l2;
    float o1a = a1a * r1 + b1v.x;
    float o1b = a1b * r1 + b1v.y;
    float o2a = a2a * r2 + b2v.x;
    float o2b = a2b * r2 + b2v.y;

    // gate logits: concat(out1,out2) @ gate_W(256x2) + gate_b
    float2 g1a = *(const float2*)(gW + 2 * ca);          // rows ca,cb
    float2 g1b = *(const float2*)(gW + 2 * cb);
    float2 g2a = *(const float2*)(gW + 2 * (128 + ca));
    float2 g2b = *(const float2*)(gW + 2 * (128 + cb));
    float p0 = o1a * g1a.x + o1b * g1b.x + o2a * g2a.x + o2b * g2b.x;
    float p1 = o1a * g1a.y + o1b * g1b.y + o2a * g2a.y + o2b * g2b.y;
    p0 = wred(p0) + gb[0];
    p1 = wred(p1) + gb[1];
    float mg = fmaxf(p0, p1);
    float eg0 = __expf(p0 - mg), eg1 = __expf(p1 - mg);
    float g0 = eg0 / (eg0 + eg1), g1 = 1.f - g0;

    float2 xv = *(const float2*)(x + (size_t)node * 128 + ca);
    float ya = xv.x + g0 * o1a + g1 * o2a;
    float yb = xv.y + g0 * o1b + g1 * o2b;

    float s  = wred(ya + yb);
    float ss = wred(ya * ya + yb * yb);
    float mean = s * (1.f / 128.f);
    float var  = ss * (1.f / 128.f) - mean * mean;
    float rstd = rsqrtf(var + LN_EPS);
    float2 gv = *(const float2*)(gamma + ca);
    float2 bv = *(const float2*)(beta + ca);
    float2 ov;
    ov.x = (ya - mean) * rstd * gv.x + bv.x;
    ov.y = (yb - mean) * rstd * gv.y + bv.y;
    *(float2*)(out + (size_t)node * 128 + ca) = ov;
}

extern "C" void kernel_launch(void* const* d_in, const int* in_sizes, int n_in,
                              void* d_out, int out_size, void* d_ws, size_t ws_size,
                              hipStream_t stream) {
    const float* x   = (const float*)d_in[0];
    const int*   ei  = (const int*)d_in[1];
    const float* W1  = (const float*)d_in[2];
    const float* b1  = (const float*)d_in[3];
    const float* as1 = (const float*)d_in[4];
    const float* ad1 = (const float*)d_in[5];
    const float* W2  = (const float*)d_in[6];
    const float* b2  = (const float*)d_in[7];
    const float* as2 = (const float*)d_in[8];
    const float* ad2 = (const float*)d_in[9];
    const float* gW  = (const float*)d_in[10];
    const float* gb  = (const float*)d_in[11];
    const float* gamma = (const float*)d_in[12];
    const float* beta  = (const float*)d_in[13];
    float* out = (float*)d_out;

    int n = in_sizes[0] / 128;
    int E = in_sizes[1] / 2;

    char* p = (char*)d_ws;
    auto take = [&](size_t bytes) {
        char* q = p;
        p += (bytes + 255) & ~(size_t)255;
        return (void*)q;
    };
    u16* wb    = (u16*)take((size_t)256 * 128 * 2);
    unsigned int* hbp = (unsigned int*)take((size_t)n * 128 * 4);
    float* es  = (float*)take((size_t)n * 8 * 4);
    float* ed  = (float*)take((size_t)n * 8 * 4);
    int* deg    = (int*)take((size_t)n * 4);
    int* offs   = (int*)take((size_t)(n + 1) * 4);
    int* cursor = (int*)take((size_t)n * 4);
    int* bsum   = (int*)take((size_t)256 * 4);
    int* ssrc   = (int*)take((size_t)(E + n) * 4);
    uint4* w    = (uint4*)take((size_t)(E + n) * 16);

    int nb = (n + 255) / 256;   // 196 (<= 256 required by k_scan)

    k_prep<<<nb, 256, 0, stream>>>(W1, W2, wb, deg, n);
    k_count<<<(E + 255) / 256, 256, 0, stream>>>(ei, deg, E);
    k_bsum<<<nb, 256, 0, stream>>>(deg, bsum, n);
    k_scan<<<nb, 256, 0, stream>>>(deg, bsum, offs, cursor, nb, n);
    k_gemm<<<(n + 63) / 64, 256, 0, stream>>>(x, wb, hbp, n);
    k_logits<<<(n * 4 + 255) / 256, 256, 0, stream>>>(hbp, as1, ad1, as2, ad2, es, ed, n);
    k_fill<<<(E + n + 255) / 256, 256, 0, stream>>>(ei, cursor, es, ed, ssrc, w, E, n);
    k_agg<<<(n + 3) / 4, 256, 0, stream>>>(offs, ssrc, hbp, w,
                                           b1, b2, gW, gb, x, gamma, beta, out, n);
}